// Round 17
// baseline (255.422 us; speedup 1.0000x reference)
//
#include <hip/hip_runtime.h>
#include <hip/hip_bf16.h>
#include <math.h>

#define MM 4096
#define KK 768
#define NBK 1024
#define QSCALE 65536.0f
#define LN2 0.6931471805599453f

typedef short bf16x8 __attribute__((ext_vector_type(8)));
typedef unsigned short u16x8 __attribute__((ext_vector_type(8)));
typedef float f32x4 __attribute__((ext_vector_type(4)));

__device__ __forceinline__ float bf2f(unsigned short u) {
  return __uint_as_float(((unsigned int)u) << 16);
}
__device__ __forceinline__ unsigned short f2bf(float f) {
  __hip_bfloat16 h = __float2bfloat16(f);
  return *(unsigned short*)&h;
}

__device__ __forceinline__ void gload16(const void* g, void* l) {
#if __has_builtin(__builtin_amdgcn_global_load_lds)
  __builtin_amdgcn_global_load_lds((__attribute__((address_space(1))) void*)g,
                                   (__attribute__((address_space(3))) void*)l,
                                   16, 0, 0);
#else
  *(bf16x8*)l = *(const bf16x8*)g;
#endif
}

// ------- normalize rows -> bf16, 4 rows/block (+min/max + acc-zero last block) ----
__global__ __launch_bounds__(256) void knorm(const float* __restrict__ emb,
                                             __hip_bfloat16* __restrict__ nb,
                                             const float* __restrict__ labels,
                                             float* __restrict__ dmm,
                                             double* __restrict__ gacc) {
  const int tid = threadIdx.x;
  if (blockIdx.x == MM / 4) {  // fused kminmax + accumulator-zero block
    if (tid < 3) gacc[tid] = 0.0;
    if (tid == 3) *(unsigned int*)(gacc + 3) = 0u;
    float mn0 = 1e30f, mx0 = -1e30f, mn1 = 1e30f, mx1 = -1e30f;
    for (int q = tid; q < MM; q += 256) {
      float2 l2 = ((const float2*)labels)[q];
      mn0 = fminf(mn0, l2.x); mx0 = fmaxf(mx0, l2.x);
      mn1 = fminf(mn1, l2.y); mx1 = fmaxf(mx1, l2.y);
    }
    for (int s = 32; s; s >>= 1) {
      mn0 = fminf(mn0, __shfl_down(mn0, s, 64));
      mx0 = fmaxf(mx0, __shfl_down(mx0, s, 64));
      mn1 = fminf(mn1, __shfl_down(mn1, s, 64));
      mx1 = fmaxf(mx1, __shfl_down(mx1, s, 64));
    }
    __shared__ float redm[4][4];
    if ((tid & 63) == 0) {
      redm[0][tid >> 6] = mn0; redm[1][tid >> 6] = mx0;
      redm[2][tid >> 6] = mn1; redm[3][tid >> 6] = mx1;
    }
    __syncthreads();
    if (tid == 0) {
      dmm[0] = fminf(fminf(redm[0][0], redm[0][1]), fminf(redm[0][2], redm[0][3]));
      dmm[1] = fmaxf(fmaxf(redm[1][0], redm[1][1]), fmaxf(redm[1][2], redm[1][3]));
      dmm[2] = fminf(fminf(redm[2][0], redm[2][1]), fminf(redm[2][2], redm[2][3]));
      dmm[3] = fmaxf(fmaxf(redm[3][0], redm[3][1]), fmaxf(redm[3][2], redm[3][3]));
    }
    return;
  }
  const int w = tid >> 6, l = tid & 63;
  const int row = blockIdx.x * 4 + w;
  const float4* e4 = (const float4*)(emb + (size_t)row * KK);
  float4 a = e4[l], b = e4[l + 64], c = e4[l + 128];
  float ss = a.x * a.x + a.y * a.y + a.z * a.z + a.w * a.w +
             b.x * b.x + b.y * b.y + b.z * b.z + b.w * b.w +
             c.x * c.x + c.y * c.y + c.z * c.z + c.w * c.w;
#pragma unroll
  for (int s = 1; s < 64; s <<= 1) ss += __shfl_xor(ss, s, 64);
  const float inv = 1.f / fmaxf(sqrtf(ss), 1e-12f);
  unsigned short* o = (unsigned short*)(nb + (size_t)row * KK);
  ushort4 o1 = {f2bf(a.x * inv), f2bf(a.y * inv), f2bf(a.z * inv), f2bf(a.w * inv)};
  ushort4 o2 = {f2bf(b.x * inv), f2bf(b.y * inv), f2bf(b.z * inv), f2bf(b.w * inv)};
  ushort4 o3 = {f2bf(c.x * inv), f2bf(c.y * inv), f2bf(c.z * inv), f2bf(c.w * inv)};
  *(ushort4*)(o + l * 4) = o1;
  *(ushort4*)(o + 256 + l * 4) = o2;
  *(ushort4*)(o + 512 + l * 4) = o3;
}

// ------ symmetric bf16 MFMA GEMM, paired 64x128 blocks (shared A-panel), BK=64 ----
union SmemP {
  struct { short As[64 * 64]; short Bs0[64 * 64]; short Bs1[64 * 64]; } s;  // 24 KB
  float tbuf[32][68];
};

__global__ __launch_bounds__(256) void kgemm_sym64p(const __hip_bfloat16* __restrict__ A,
                                                    unsigned short* __restrict__ out,
                                                    float* __restrict__ srow) {
  __shared__ __align__(16) SmemP sm;
  const int tid = threadIdx.x;
  const int w = tid >> 6, l = tid & 63;
  const int wr = w >> 1, wc = w & 1;
  // decode pair-block: row by has ceil((64-by)/2) pair-blocks
  int rem = blockIdx.x, by = 0;
  while (rem >= ((65 - by) >> 1)) { rem -= (65 - by) >> 1; ++by; }
  const int bx0 = by + 2 * rem;
  const int bx1 = bx0 + 1;
  const bool has2 = (bx1 < 64);
  const int row0 = by * 64;
  const int col0t[2] = {bx0 * 64, (has2 ? bx1 : bx0) * 64};
  const int bxt[2] = {bx0, bx1};
  const short* Ag = (const short*)A;

  f32x4 acc[2][2][2];  // [tile][mi][ni]
#pragma unroll
  for (int t = 0; t < 2; ++t)
#pragma unroll
    for (int mi = 0; mi < 2; ++mi)
#pragma unroll
      for (int ni = 0; ni < 2; ++ni) acc[t][mi][ni] = (f32x4){0.f, 0.f, 0.f, 0.f};

  const int r0 = tid >> 3, s0 = tid & 7;
  const int sx = ((s0 ^ (r0 & 7)) * 8);          // pre-swizzled source column seg
  const int lr = l & 15, kb = (l >> 4) * 8;
  const int xr = (lr & 7) << 3;                  // read-side XOR swizzle

  for (int k0 = 0; k0 < KK; k0 += 64) {
    __syncthreads();
    gload16(Ag + (size_t)(row0 + r0) * KK + k0 + sx, &sm.s.As[tid * 8]);
    gload16(Ag + (size_t)(row0 + 32 + r0) * KK + k0 + sx, &sm.s.As[(tid + 256) * 8]);
    gload16(Ag + (size_t)(col0t[0] + r0) * KK + k0 + sx, &sm.s.Bs0[tid * 8]);
    gload16(Ag + (size_t)(col0t[0] + 32 + r0) * KK + k0 + sx, &sm.s.Bs0[(tid + 256) * 8]);
    gload16(Ag + (size_t)(col0t[1] + r0) * KK + k0 + sx, &sm.s.Bs1[tid * 8]);
    gload16(Ag + (size_t)(col0t[1] + 32 + r0) * KK + k0 + sx, &sm.s.Bs1[(tid + 256) * 8]);
    __syncthreads();
    bf16x8 av[2][2];
#pragma unroll
    for (int mi = 0; mi < 2; ++mi)
#pragma unroll
      for (int kh = 0; kh < 2; ++kh)
        av[mi][kh] = *(const bf16x8*)&sm.s.As[(wr * 32 + mi * 16 + lr) * 64 +
                                              ((kh * 32 + kb) ^ xr)];
    {
      bf16x8 bv[2][2];
#pragma unroll
      for (int ni = 0; ni < 2; ++ni)
#pragma unroll
        for (int kh = 0; kh < 2; ++kh)
          bv[ni][kh] = *(const bf16x8*)&sm.s.Bs0[(wc * 32 + ni * 16 + lr) * 64 +
                                                 ((kh * 32 + kb) ^ xr)];
#pragma unroll
      for (int kh = 0; kh < 2; ++kh)
#pragma unroll
        for (int mi = 0; mi < 2; ++mi)
#pragma unroll
          for (int ni = 0; ni < 2; ++ni)
            acc[0][mi][ni] = __builtin_amdgcn_mfma_f32_16x16x32_bf16(
                av[mi][kh], bv[ni][kh], acc[0][mi][ni], 0, 0, 0);
    }
    {
      bf16x8 bv[2][2];
#pragma unroll
      for (int ni = 0; ni < 2; ++ni)
#pragma unroll
        for (int kh = 0; kh < 2; ++kh)
          bv[ni][kh] = *(const bf16x8*)&sm.s.Bs1[(wc * 32 + ni * 16 + lr) * 64 +
                                                 ((kh * 32 + kb) ^ xr)];
#pragma unroll
      for (int kh = 0; kh < 2; ++kh)
#pragma unroll
        for (int mi = 0; mi < 2; ++mi)
#pragma unroll
          for (int ni = 0; ni < 2; ++ni)
            acc[1][mi][ni] = __builtin_amdgcn_mfma_f32_16x16x32_bf16(
                av[mi][kh], bv[ni][kh], acc[1][mi][ni], 0, 0, 0);
    }
  }

  const int quad = l >> 4;

#pragma unroll
  for (int t = 0; t < 2; ++t) {
    const bool active = (t == 0) || has2;
    const bool diag = (t == 0) && (bx0 == by);
    const int col0 = col0t[t];

    // row-sums: slot bxt*2 + wc
#pragma unroll
    for (int mi = 0; mi < 2; ++mi) {
#pragma unroll
      for (int r = 0; r < 4; ++r) {
        const int grow = row0 + wr * 32 + mi * 16 + quad * 4 + r;
        float rsum = 0.f;
#pragma unroll
        for (int ni = 0; ni < 2; ++ni) {
          const int gcol = col0 + wc * 32 + ni * 16 + lr;
          rsum += (diag && gcol == grow) ? 0.f : acc[t][mi][ni][r];
        }
#pragma unroll
        for (int mask = 1; mask < 16; mask <<= 1) rsum += __shfl_xor(rsum, mask, 64);
        if (active && lr == 0)
          srow[(size_t)grow * 128 + bxt[t] * 2 + wc] = rsum / 0.1f;
      }
    }

    // mirrored row-sums = tile column sums: slot by*2 + wr
    if (!diag) {
#pragma unroll
      for (int ni = 0; ni < 2; ++ni) {
        float csum = 0.f;
#pragma unroll
        for (int mi = 0; mi < 2; ++mi)
#pragma unroll
          for (int r = 0; r < 4; ++r) csum += acc[t][mi][ni][r];
        csum += __shfl_xor(csum, 16, 64);
        csum += __shfl_xor(csum, 32, 64);
        if (active && quad == 0)
          srow[(size_t)(col0 + wc * 32 + ni * 16 + l) * 128 + by * 2 + wr] =
              csum / 0.1f;
      }
    }

    // exp in place
#pragma unroll
    for (int mi = 0; mi < 2; ++mi)
#pragma unroll
      for (int ni = 0; ni < 2; ++ni)
#pragma unroll
        for (int r = 0; r < 4; ++r)
          acc[t][mi][ni][r] = __expf(acc[t][mi][ni][r] / 0.1f);

    // normal store (bf16)
    if (active) {
#pragma unroll
      for (int mi = 0; mi < 2; ++mi)
#pragma unroll
        for (int r = 0; r < 4; ++r) {
          const int grow = row0 + wr * 32 + mi * 16 + quad * 4 + r;
#pragma unroll
          for (int ni = 0; ni < 2; ++ni)
            out[(size_t)grow * MM + col0 + wc * 32 + ni * 16 + lr] =
                f2bf(acc[t][mi][ni][r]);
        }
    }

    // mirrored (transposed) store via LDS, 2 passes of 32 rows
    if (!diag) {
#pragma unroll
      for (int p = 0; p < 2; ++p) {
        __syncthreads();
        if (wc == p) {
#pragma unroll
          for (int ni = 0; ni < 2; ++ni) {
            const int ltr = ni * 16 + lr;
#pragma unroll
            for (int mi = 0; mi < 2; ++mi) {
              const int cbase = wr * 32 + mi * 16 + quad * 4;
#pragma unroll
              for (int r = 0; r < 4; ++r)
                sm.tbuf[ltr][cbase + r] = acc[t][mi][ni][r];
            }
          }
        }
        __syncthreads();
        if (active) {
          const int trow = tid >> 3;
          const int cseg = (tid & 7) * 8;
          const int gtr = col0 + p * 32 + trow;
          u16x8 vv;
#pragma unroll
          for (int q = 0; q < 8; ++q) vv[q] = f2bf(sm.tbuf[trow][cseg + q]);
          *(u16x8*)(out + (size_t)gtr * MM + row0 + cseg) = vv;
        }
      }
    }
  }
}

// ---------------- chunked fallback GEMM (small workspace only) ----------
__global__ __launch_bounds__(256) void kgemm(const __hip_bfloat16* __restrict__ A,
                                             int rowBase,
                                             unsigned short* __restrict__ out,
                                             float* __restrict__ srow) {
  __shared__ __align__(16) short As[128 * 32];
  __shared__ __align__(16) short Bs[128 * 32];
  const int tid = threadIdx.x;
  const int w = tid >> 6, l = tid & 63;
  const int wr = w >> 1, wc = w & 1;
  const int bx = blockIdx.x;
  const int row0 = rowBase + blockIdx.y * 128;
  const int col0 = bx * 128;
  const short* Ag = (const short*)A;

  f32x4 acc[4][4];
#pragma unroll
  for (int mi = 0; mi < 4; ++mi)
#pragma unroll
    for (int ni = 0; ni < 4; ++ni) acc[mi][ni] = (f32x4){0.f, 0.f, 0.f, 0.f};

  const int r0 = tid >> 2, s0 = tid & 3;
  const int r1 = (tid + 256) >> 2;
  const int lrow = l & 15, kb = (l >> 4) * 8;

  for (int k0 = 0; k0 < KK; k0 += 32) {
    __syncthreads();
    gload16(Ag + (size_t)(row0 + r0) * KK + k0 + s0 * 8, &As[tid * 8]);
    gload16(Ag + (size_t)(row0 + r1) * KK + k0 + s0 * 8, &As[(tid + 256) * 8]);
    gload16(Ag + (size_t)(col0 + r0) * KK + k0 + s0 * 8, &Bs[tid * 8]);
    gload16(Ag + (size_t)(col0 + r1) * KK + k0 + s0 * 8, &Bs[(tid + 256) * 8]);
    __syncthreads();
    bf16x8 av[4], bv[4];
#pragma unroll
    for (int mi = 0; mi < 4; ++mi)
      av[mi] = *(const bf16x8*)&As[(wr * 64 + mi * 16 + lrow) * 32 + kb];
#pragma unroll
    for (int ni = 0; ni < 4; ++ni)
      bv[ni] = *(const bf16x8*)&Bs[(wc * 64 + ni * 16 + lrow) * 32 + kb];
#pragma unroll
    for (int mi = 0; mi < 4; ++mi)
#pragma unroll
      for (int ni = 0; ni < 4; ++ni)
        acc[mi][ni] = __builtin_amdgcn_mfma_f32_16x16x32_bf16(av[mi], bv[ni],
                                                              acc[mi][ni], 0, 0, 0);
  }

  const int quad = l >> 4;
#pragma unroll
  for (int mi = 0; mi < 4; ++mi) {
#pragma unroll
    for (int r = 0; r < 4; ++r) {
      const int grow = row0 + wr * 64 + mi * 16 + quad * 4 + r;
      float rsum = 0.f;
#pragma unroll
      for (int ni = 0; ni < 4; ++ni) {
        const int gcol = col0 + wc * 64 + ni * 16 + lrow;
        float a = acc[mi][ni][r];
        out[(size_t)(grow - rowBase) * MM + gcol] = f2bf(__expf(a / 0.1f));
        rsum += (gcol == grow) ? 0.f : a;
      }
#pragma unroll
      for (int mask = 1; mask < 16; mask <<= 1) rsum += __shfl_xor(rsum, mask, 64);
      if (lrow == 0) srow[(size_t)grow * 128 + bx * 2 + wc] = rsum / 0.1f;
    }
  }
}

// ---- per-row loss: dual-dim u64 histogram + fused srow sum + atomic finale ------
__global__ __launch_bounds__(256) void kloss(const unsigned short* __restrict__ expb,
                                             int rowBase,
                                             const float* __restrict__ labels,
                                             const float* __restrict__ dmm,
                                             const float* __restrict__ srow,
                                             double* __restrict__ gacc,
                                             float* __restrict__ outv) {
  const int i = rowBase + blockIdx.x;
  const unsigned short* row = expb + (size_t)blockIdx.x * MM;
  __shared__ __align__(16) unsigned long long histU[2 * NBK];
  __shared__ unsigned long long wsumU[4];
  __shared__ float redf[4];
  __shared__ float redsr[4];
  const int tid = threadIdx.x;
  const int lane = tid & 63, wid = tid >> 6;
  const int m0 = tid * 16;
  const int b0 = tid * 8;

  // fused srow row-sum (512 B coalesced, hidden under histogram work)
  float sv = (tid < 128) ? srow[(size_t)i * 128 + tid] : 0.f;
  for (int s = 32; s; s >>= 1) sv += __shfl_down(sv, s, 64);
  if (lane == 0) redsr[wid] = sv;

  const float c0 = labels[(size_t)i * 2], c1 = labels[(size_t)i * 2 + 1];
  const float tmax0 = fmaxf(fmaxf(c0 - dmm[0], dmm[1] - c0), 1e-30f);
  const float tmax1 = fmaxf(fmaxf(c1 - dmm[2], dmm[3] - c1), 1e-30f);
  const float scale0 = (float)NBK / tmax0;
  const float scale1 = (float)NBK / tmax1;

#pragma unroll
  for (int q = 0; q < 4; ++q)
    ((uint4*)histU)[tid + 256 * q] = (uint4){0, 0, 0, 0};
  __syncthreads();

  {
    u16x8 a = *(const u16x8*)(row + m0);
    u16x8 bq = *(const u16x8*)(row + m0 + 8);
    const float4* lp4 = (const float4*)(labels + (size_t)m0 * 2);
#pragma unroll
    for (int q = 0; q < 8; ++q) {
      float4 v4 = lp4[q];
      const unsigned short r0u = (2 * q < 8) ? a[2 * q] : bq[2 * q - 8];
      const unsigned short r1u = (2 * q + 1 < 8) ? a[2 * q + 1] : bq[2 * q + 1 - 8];
      const unsigned long long g0 =
          (unsigned long long)(unsigned int)(bf2f(r0u) * QSCALE + 0.5f) | (1ULL << 32);
      const unsigned long long g1 =
          (unsigned long long)(unsigned int)(bf2f(r1u) * QSCALE + 0.5f) | (1ULL << 32);
      const int a0 = min((int)(fabsf(v4.x - c0) * scale0), NBK - 1);
      const int a1 = min((int)(fabsf(v4.y - c1) * scale1), NBK - 1);
      const int b2 = min((int)(fabsf(v4.z - c0) * scale0), NBK - 1);
      const int b3 = min((int)(fabsf(v4.w - c1) * scale1), NBK - 1);
      atomicAdd(&histU[a0], g0);
      atomicAdd(&histU[NBK + a1], g0);
      atomicAdd(&histU[b2], g1);
      atomicAdd(&histU[NBK + b3], g1);
    }
  }
  __syncthreads();

  // u64 suffix scan over own 8 buckets; waves 0-1 = dim0, waves 2-3 = dim1
  unsigned long long hh[8];
#pragma unroll
  for (int q = 0; q < 4; ++q) {
    uint4 t4 = *(const uint4*)&histU[b0 + 2 * q];
    hh[2 * q] = (unsigned long long)t4.x | ((unsigned long long)t4.y << 32);
    hh[2 * q + 1] = (unsigned long long)t4.z | ((unsigned long long)t4.w << 32);
  }
  unsigned long long S = 0;
#pragma unroll
  for (int u = 0; u < 8; ++u) S += hh[u];
  unsigned long long v = S;
#pragma unroll
  for (int s = 1; s < 64; s <<= 1) {
    unsigned long long t2 = __shfl_down(v, s, 64);
    if (lane + s < 64) v += t2;
  }
  if (lane == 0) wsumU[wid] = v;
  __syncthreads();
  unsigned long long woff = (wid == 0) ? wsumU[1] : ((wid == 2) ? wsumU[3] : 0ULL);
  unsigned long long run = woff + (v - S);

  float acc2 = 0.f;
#pragma unroll
  for (int u = 7; u >= 0; --u) {
    run += hh[u];
    const float nf = (float)(unsigned int)(hh[u] >> 32);
    const float sufq = (float)(unsigned int)run;
    acc2 += nf * __log2f(fmaxf(sufq, 1.f));
  }

  for (int s = 32; s; s >>= 1) acc2 += __shfl_down(acc2, s, 64);
  if (lane == 0) redf[wid] = acc2;
  __syncthreads();
  if (tid == 0) {
    const float tf0 = (float)(unsigned int)(wsumU[0] + wsumU[1]);
    const float tf1 = (float)(unsigned int)(wsumU[2] + wsumU[3]);
    const float p0 = (redf[0] + redf[1] - 65536.f - __log2f(tf0) + 16.f) * LN2;
    const float p1 = (redf[2] + redf[3] - 65536.f - __log2f(tf1) + 16.f) * LN2;
    const float psr = redsr[0] + redsr[1];
    atomicAdd(&gacc[0], (double)p0);
    atomicAdd(&gacc[1], (double)p1);
    atomicAdd(&gacc[2], (double)psr);
    __threadfence();
    unsigned int tk = atomicAdd((unsigned int*)(gacc + 3), 1u);
    if (tk == MM - 1) {  // last block finishes the reduction
      const double a0 = atomicAdd(&gacc[0], 0.0);
      const double a1 = atomicAdd(&gacc[1], 0.0);
      const double asr = atomicAdd(&gacc[2], 0.0);
      const double n = (double)MM * (double)(MM - 1);
      outv[0] = (float)((a0 - asr) / n);
      outv[1] = (float)((a1 - asr) / n);
    }
  }
}

extern "C" void kernel_launch(void* const* d_in, const int* in_sizes, int n_in,
                              void* d_out, int out_size, void* d_ws, size_t ws_size,
                              hipStream_t stream) {
  const float* emb = (const float*)d_in[0];
  const float* labels = (const float*)d_in[1];
  float* out = (float*)d_out;
  char* ws = (char*)d_ws;

  size_t off = 0;
  auto alloc = [&](size_t bytes) {
    void* p = ws + off;
    off = (off + bytes + 255) & ~(size_t)255;
    return p;
  };
  __hip_bfloat16* nb = (__hip_bfloat16*)alloc((size_t)MM * KK * 2);
  float* dmm = (float*)alloc(4 * 4);
  double* gacc = (double*)alloc(4 * 8);  // [0..2] partials, [3] ticket
  float* srow = (float*)alloc((size_t)MM * 128 * 4);
  size_t fixed = off;

  size_t avail = (ws_size > fixed) ? (ws_size - fixed) : 0;
  long long cr = (long long)(avail / ((size_t)MM * 2));
  cr = (cr / 128) * 128;
  if (cr > MM) cr = MM;
  if (cr < 128) cr = 128;
  int chunk_rows = (int)cr;
  unsigned short* expb = (unsigned short*)(ws + fixed);

  knorm<<<MM / 4 + 1, 256, 0, stream>>>(emb, nb, labels, dmm, gacc);

  if (chunk_rows == MM) {
    kgemm_sym64p<<<1056, 256, 0, stream>>>(nb, expb, srow);
    kloss<<<MM, 256, 0, stream>>>(expb, 0, labels, dmm, srow, gacc, out);
  } else {
    hipMemsetAsync(srow, 0, (size_t)MM * 128 * 4, stream);
    for (int base = 0; base < MM; base += chunk_rows) {
      int rows = MM - base < chunk_rows ? MM - base : chunk_rows;
      kgemm<<<dim3(MM / 128, rows / 128), 256, 0, stream>>>(nb, base, expb, srow);
      kloss<<<rows, 256, 0, stream>>>(expb, base, labels, dmm, srow, gacc, out);
    }
  }
}

// Round 18
// 69.224 us; speedup vs baseline: 3.6898x; 3.6898x over previous
//
#include <hip/hip_runtime.h>
#include <hip/hip_bf16.h>
#include <math.h>

#define MM 4096
#define KK 768
#define NB64 64
#define NBK 1024
#define QSCALE 65536.0f
#define LN2 0.6931471805599453f

typedef short bf16x8 __attribute__((ext_vector_type(8)));
typedef unsigned short u16x8 __attribute__((ext_vector_type(8)));
typedef float f32x4 __attribute__((ext_vector_type(4)));

__device__ __forceinline__ float bf2f(unsigned short u) {
  return __uint_as_float(((unsigned int)u) << 16);
}
__device__ __forceinline__ unsigned short f2bf(float f) {
  __hip_bfloat16 h = __float2bfloat16(f);
  return *(unsigned short*)&h;
}

__device__ __forceinline__ void gload16(const void* g, void* l) {
#if __has_builtin(__builtin_amdgcn_global_load_lds)
  __builtin_amdgcn_global_load_lds((__attribute__((address_space(1))) void*)g,
                                   (__attribute__((address_space(3))) void*)l,
                                   16, 0, 0);
#else
  *(bf16x8*)l = *(const bf16x8*)g;
#endif
}

// ------- normalize rows -> bf16, 4 rows/block wave-local (+min/max last block) ----
__global__ __launch_bounds__(256) void knorm(const float* __restrict__ emb,
                                             __hip_bfloat16* __restrict__ nb,
                                             const float* __restrict__ labels,
                                             float* __restrict__ dmm) {
  const int tid = threadIdx.x;
  if (blockIdx.x == MM / 4) {  // fused kminmax block
    float mn0 = 1e30f, mx0 = -1e30f, mn1 = 1e30f, mx1 = -1e30f;
    for (int q = tid; q < MM; q += 256) {
      float2 l2 = ((const float2*)labels)[q];
      mn0 = fminf(mn0, l2.x); mx0 = fmaxf(mx0, l2.x);
      mn1 = fminf(mn1, l2.y); mx1 = fmaxf(mx1, l2.y);
    }
    for (int s = 32; s; s >>= 1) {
      mn0 = fminf(mn0, __shfl_down(mn0, s, 64));
      mx0 = fmaxf(mx0, __shfl_down(mx0, s, 64));
      mn1 = fminf(mn1, __shfl_down(mn1, s, 64));
      mx1 = fmaxf(mx1, __shfl_down(mx1, s, 64));
    }
    __shared__ float redm[4][4];
    if ((tid & 63) == 0) {
      redm[0][tid >> 6] = mn0; redm[1][tid >> 6] = mx0;
      redm[2][tid >> 6] = mn1; redm[3][tid >> 6] = mx1;
    }
    __syncthreads();
    if (tid == 0) {
      dmm[0] = fminf(fminf(redm[0][0], redm[0][1]), fminf(redm[0][2], redm[0][3]));
      dmm[1] = fmaxf(fmaxf(redm[1][0], redm[1][1]), fmaxf(redm[1][2], redm[1][3]));
      dmm[2] = fminf(fminf(redm[2][0], redm[2][1]), fminf(redm[2][2], redm[2][3]));
      dmm[3] = fmaxf(fmaxf(redm[3][0], redm[3][1]), fmaxf(redm[3][2], redm[3][3]));
    }
    return;
  }
  const int w = tid >> 6, l = tid & 63;
  const int row = blockIdx.x * 4 + w;
  const float4* e4 = (const float4*)(emb + (size_t)row * KK);
  float4 a = e4[l], b = e4[l + 64], c = e4[l + 128];
  float ss = a.x * a.x + a.y * a.y + a.z * a.z + a.w * a.w +
             b.x * b.x + b.y * b.y + b.z * b.z + b.w * b.w +
             c.x * c.x + c.y * c.y + c.z * c.z + c.w * c.w;
#pragma unroll
  for (int s = 1; s < 64; s <<= 1) ss += __shfl_xor(ss, s, 64);
  const float inv = 1.f / fmaxf(sqrtf(ss), 1e-12f);
  unsigned short* o = (unsigned short*)(nb + (size_t)row * KK);
  ushort4 o1 = {f2bf(a.x * inv), f2bf(a.y * inv), f2bf(a.z * inv), f2bf(a.w * inv)};
  ushort4 o2 = {f2bf(b.x * inv), f2bf(b.y * inv), f2bf(b.z * inv), f2bf(b.w * inv)};
  ushort4 o3 = {f2bf(c.x * inv), f2bf(c.y * inv), f2bf(c.z * inv), f2bf(c.w * inv)};
  *(ushort4*)(o + l * 4) = o1;
  *(ushort4*)(o + 256 + l * 4) = o2;
  *(ushort4*)(o + 512 + l * 4) = o3;
}

// ---------------- symmetric bf16 MFMA GEMM, 64x64 tiles, BK=64 (proven form) -----
union SmemU64 {
  struct { short As[64 * 64]; short Bs[64 * 64]; } s;
  float tbuf[32][68];
};

__global__ __launch_bounds__(256) void kgemm_sym64(const __hip_bfloat16* __restrict__ A,
                                                   unsigned short* __restrict__ out,
                                                   float* __restrict__ srow) {
  __shared__ __align__(16) SmemU64 sm;
  const int tid = threadIdx.x;
  const int w = tid >> 6, l = tid & 63;
  const int wr = w >> 1, wc = w & 1;
  // decode triangular block index -> (by, bx), bx >= by
  const int b = blockIdx.x;
  int by = (int)((129.0f - sqrtf(16641.0f - 8.0f * (float)b)) * 0.5f);
  by = min(max(by, 0), 63);
  while (by > 0 && (by * (129 - by)) / 2 > b) --by;
  while (by < 63 && (((by + 1) * (129 - (by + 1))) / 2) <= b) ++by;
  const int bx = by + (b - (by * (129 - by)) / 2);
  const int row0 = by * 64, col0 = bx * 64;
  const short* Ag = (const short*)A;

  f32x4 acc[2][2];
#pragma unroll
  for (int mi = 0; mi < 2; ++mi)
#pragma unroll
    for (int ni = 0; ni < 2; ++ni) acc[mi][ni] = (f32x4){0.f, 0.f, 0.f, 0.f};

  const int r0 = tid >> 3, s0 = tid & 7;
  const int sx = ((s0 ^ (r0 & 7)) * 8);          // pre-swizzled source column seg
  const int lr = l & 15, kb = (l >> 4) * 8;
  const int xr = (lr & 7) << 3;                  // read-side XOR swizzle

  for (int k0 = 0; k0 < KK; k0 += 64) {
    __syncthreads();
    gload16(Ag + (size_t)(row0 + r0) * KK + k0 + sx, &sm.s.As[tid * 8]);
    gload16(Ag + (size_t)(row0 + 32 + r0) * KK + k0 + sx, &sm.s.As[(tid + 256) * 8]);
    gload16(Ag + (size_t)(col0 + r0) * KK + k0 + sx, &sm.s.Bs[tid * 8]);
    gload16(Ag + (size_t)(col0 + 32 + r0) * KK + k0 + sx, &sm.s.Bs[(tid + 256) * 8]);
    __syncthreads();
    bf16x8 av[2][2], bv[2][2];
#pragma unroll
    for (int mi = 0; mi < 2; ++mi)
#pragma unroll
      for (int kh = 0; kh < 2; ++kh)
        av[mi][kh] = *(const bf16x8*)&sm.s.As[(wr * 32 + mi * 16 + lr) * 64 +
                                              ((kh * 32 + kb) ^ xr)];
#pragma unroll
    for (int ni = 0; ni < 2; ++ni)
#pragma unroll
      for (int kh = 0; kh < 2; ++kh)
        bv[ni][kh] = *(const bf16x8*)&sm.s.Bs[(wc * 32 + ni * 16 + lr) * 64 +
                                              ((kh * 32 + kb) ^ xr)];
#pragma unroll
    for (int kh = 0; kh < 2; ++kh)
#pragma unroll
      for (int mi = 0; mi < 2; ++mi)
#pragma unroll
        for (int ni = 0; ni < 2; ++ni)
          acc[mi][ni] = __builtin_amdgcn_mfma_f32_16x16x32_bf16(av[mi][kh], bv[ni][kh],
                                                                acc[mi][ni], 0, 0, 0);
  }

  const int quad = l >> 4;
  const bool diag = (bx == by);

  // row-sums: slot bx*2 + wc
#pragma unroll
  for (int mi = 0; mi < 2; ++mi) {
#pragma unroll
    for (int r = 0; r < 4; ++r) {
      const int grow = row0 + wr * 32 + mi * 16 + quad * 4 + r;
      float rsum = 0.f;
#pragma unroll
      for (int ni = 0; ni < 2; ++ni) {
        const int gcol = col0 + wc * 32 + ni * 16 + lr;
        rsum += (diag && gcol == grow) ? 0.f : acc[mi][ni][r];
      }
#pragma unroll
      for (int mask = 1; mask < 16; mask <<= 1) rsum += __shfl_xor(rsum, mask, 64);
      if (lr == 0) srow[(size_t)grow * 128 + bx * 2 + wc] = rsum / 0.1f;
    }
  }

  // mirrored row-sums = tile column sums: slot by*2 + wr
  if (!diag) {
#pragma unroll
    for (int ni = 0; ni < 2; ++ni) {
      float csum = 0.f;
#pragma unroll
      for (int mi = 0; mi < 2; ++mi)
#pragma unroll
        for (int r = 0; r < 4; ++r) csum += acc[mi][ni][r];
      csum += __shfl_xor(csum, 16, 64);
      csum += __shfl_xor(csum, 32, 64);
      if (quad == 0)
        srow[(size_t)(col0 + wc * 32 + ni * 16 + l) * 128 + by * 2 + wr] = csum / 0.1f;
    }
  }

  // exp in place
#pragma unroll
  for (int mi = 0; mi < 2; ++mi)
#pragma unroll
    for (int ni = 0; ni < 2; ++ni)
#pragma unroll
      for (int r = 0; r < 4; ++r)
        acc[mi][ni][r] = __expf(acc[mi][ni][r] / 0.1f);

  // normal store (bf16)
#pragma unroll
  for (int mi = 0; mi < 2; ++mi)
#pragma unroll
    for (int r = 0; r < 4; ++r) {
      const int grow = row0 + wr * 32 + mi * 16 + quad * 4 + r;
#pragma unroll
      for (int ni = 0; ni < 2; ++ni)
        out[(size_t)grow * MM + col0 + wc * 32 + ni * 16 + lr] = f2bf(acc[mi][ni][r]);
    }

  // mirrored (transposed) store via LDS, 2 passes of 32 rows
  if (!diag) {
#pragma unroll
    for (int p = 0; p < 2; ++p) {
      __syncthreads();
      if (wc == p) {
#pragma unroll
        for (int ni = 0; ni < 2; ++ni) {
          const int ltr = ni * 16 + lr;
#pragma unroll
          for (int mi = 0; mi < 2; ++mi) {
            const int cbase = wr * 32 + mi * 16 + quad * 4;
#pragma unroll
            for (int r = 0; r < 4; ++r)
              sm.tbuf[ltr][cbase + r] = acc[mi][ni][r];
          }
        }
      }
      __syncthreads();
      const int trow = tid >> 3;
      const int cseg = (tid & 7) * 8;
      const int gtr = col0 + p * 32 + trow;
      u16x8 vv;
#pragma unroll
      for (int q = 0; q < 8; ++q) vv[q] = f2bf(sm.tbuf[trow][cseg + q]);
      *(u16x8*)(out + (size_t)gtr * MM + row0 + cseg) = vv;
    }
  }
}

// ---------------- chunked fallback GEMM (small workspace only) ----------
__global__ __launch_bounds__(256) void kgemm(const __hip_bfloat16* __restrict__ A,
                                             int rowBase,
                                             unsigned short* __restrict__ out,
                                             float* __restrict__ srow) {
  __shared__ __align__(16) short As[128 * 32];
  __shared__ __align__(16) short Bs[128 * 32];
  const int tid = threadIdx.x;
  const int w = tid >> 6, l = tid & 63;
  const int wr = w >> 1, wc = w & 1;
  const int bx = blockIdx.x;
  const int row0 = rowBase + blockIdx.y * 128;
  const int col0 = bx * 128;
  const short* Ag = (const short*)A;

  f32x4 acc[4][4];
#pragma unroll
  for (int mi = 0; mi < 4; ++mi)
#pragma unroll
    for (int ni = 0; ni < 4; ++ni) acc[mi][ni] = (f32x4){0.f, 0.f, 0.f, 0.f};

  const int r0 = tid >> 2, s0 = tid & 3;
  const int r1 = (tid + 256) >> 2;
  const int lrow = l & 15, kb = (l >> 4) * 8;

  for (int k0 = 0; k0 < KK; k0 += 32) {
    __syncthreads();
    gload16(Ag + (size_t)(row0 + r0) * KK + k0 + s0 * 8, &As[tid * 8]);
    gload16(Ag + (size_t)(row0 + r1) * KK + k0 + s0 * 8, &As[(tid + 256) * 8]);
    gload16(Ag + (size_t)(col0 + r0) * KK + k0 + s0 * 8, &Bs[tid * 8]);
    gload16(Ag + (size_t)(col0 + r1) * KK + k0 + s0 * 8, &Bs[(tid + 256) * 8]);
    __syncthreads();
    bf16x8 av[4], bv[4];
#pragma unroll
    for (int mi = 0; mi < 4; ++mi)
      av[mi] = *(const bf16x8*)&As[(wr * 64 + mi * 16 + lrow) * 32 + kb];
#pragma unroll
    for (int ni = 0; ni < 4; ++ni)
      bv[ni] = *(const bf16x8*)&Bs[(wc * 64 + ni * 16 + lrow) * 32 + kb];
#pragma unroll
    for (int mi = 0; mi < 4; ++mi)
#pragma unroll
      for (int ni = 0; ni < 4; ++ni)
        acc[mi][ni] = __builtin_amdgcn_mfma_f32_16x16x32_bf16(av[mi], bv[ni],
                                                              acc[mi][ni], 0, 0, 0);
  }

  const int quad = l >> 4;
#pragma unroll
  for (int mi = 0; mi < 4; ++mi) {
#pragma unroll
    for (int r = 0; r < 4; ++r) {
      const int grow = row0 + wr * 64 + mi * 16 + quad * 4 + r;
      float rsum = 0.f;
#pragma unroll
      for (int ni = 0; ni < 4; ++ni) {
        const int gcol = col0 + wc * 64 + ni * 16 + lrow;
        float a = acc[mi][ni][r];
        out[(size_t)(grow - rowBase) * MM + gcol] = f2bf(__expf(a / 0.1f));
        rsum += (gcol == grow) ? 0.f : a;
      }
#pragma unroll
      for (int mask = 1; mask < 16; mask <<= 1) rsum += __shfl_xor(rsum, mask, 64);
      if (lrow == 0) srow[(size_t)grow * 128 + bx * 2 + wc] = rsum / 0.1f;
    }
  }
}

// ---- per-row loss: dual-dim u64 (count|qsum) histogram + fused srow row-sum -----
__global__ __launch_bounds__(256) void kloss(const unsigned short* __restrict__ expb,
                                             int rowBase,
                                             const float* __restrict__ labels,
                                             const float* __restrict__ dmm,
                                             const float* __restrict__ srow,
                                             float* __restrict__ part_logd,
                                             float* __restrict__ part_sr) {
  const int i = rowBase + blockIdx.x;
  const unsigned short* row = expb + (size_t)blockIdx.x * MM;
  __shared__ __align__(16) unsigned long long histU[2 * NBK];
  __shared__ unsigned long long wsumU[4];
  __shared__ float redf[4];
  __shared__ float redsr[4];
  const int tid = threadIdx.x;
  const int lane = tid & 63, wid = tid >> 6;
  const int m0 = tid * 16;
  const int b0 = tid * 8;

  // fused srow row-sum (512 B coalesced, hidden under histogram work)
  float sv = (tid < 128) ? srow[(size_t)i * 128 + tid] : 0.f;
  for (int s = 32; s; s >>= 1) sv += __shfl_down(sv, s, 64);
  if (lane == 0) redsr[wid] = sv;

  const float c0 = labels[(size_t)i * 2], c1 = labels[(size_t)i * 2 + 1];
  const float tmax0 = fmaxf(fmaxf(c0 - dmm[0], dmm[1] - c0), 1e-30f);
  const float tmax1 = fmaxf(fmaxf(c1 - dmm[2], dmm[3] - c1), 1e-30f);
  const float scale0 = (float)NBK / tmax0;
  const float scale1 = (float)NBK / tmax1;

#pragma unroll
  for (int q = 0; q < 4; ++q)
    ((uint4*)histU)[tid + 256 * q] = (uint4){0, 0, 0, 0};
  __syncthreads();

  {
    u16x8 a = *(const u16x8*)(row + m0);
    u16x8 bq = *(const u16x8*)(row + m0 + 8);
    const float4* lp4 = (const float4*)(labels + (size_t)m0 * 2);
#pragma unroll
    for (int q = 0; q < 8; ++q) {
      float4 v4 = lp4[q];
      const unsigned short r0u = (2 * q < 8) ? a[2 * q] : bq[2 * q - 8];
      const unsigned short r1u = (2 * q + 1 < 8) ? a[2 * q + 1] : bq[2 * q + 1 - 8];
      const unsigned long long g0 =
          (unsigned long long)(unsigned int)(bf2f(r0u) * QSCALE + 0.5f) | (1ULL << 32);
      const unsigned long long g1 =
          (unsigned long long)(unsigned int)(bf2f(r1u) * QSCALE + 0.5f) | (1ULL << 32);
      const int a0 = min((int)(fabsf(v4.x - c0) * scale0), NBK - 1);
      const int a1 = min((int)(fabsf(v4.y - c1) * scale1), NBK - 1);
      const int b2 = min((int)(fabsf(v4.z - c0) * scale0), NBK - 1);
      const int b3 = min((int)(fabsf(v4.w - c1) * scale1), NBK - 1);
      atomicAdd(&histU[a0], g0);
      atomicAdd(&histU[NBK + a1], g0);
      atomicAdd(&histU[b2], g1);
      atomicAdd(&histU[NBK + b3], g1);
    }
  }
  __syncthreads();

  // u64 suffix scan over own 8 buckets; waves 0-1 = dim0, waves 2-3 = dim1
  unsigned long long hh[8];
#pragma unroll
  for (int q = 0; q < 4; ++q) {
    uint4 t4 = *(const uint4*)&histU[b0 + 2 * q];
    hh[2 * q] = (unsigned long long)t4.x | ((unsigned long long)t4.y << 32);
    hh[2 * q + 1] = (unsigned long long)t4.z | ((unsigned long long)t4.w << 32);
  }
  unsigned long long S = 0;
#pragma unroll
  for (int u = 0; u < 8; ++u) S += hh[u];
  unsigned long long v = S;
#pragma unroll
  for (int s = 1; s < 64; s <<= 1) {
    unsigned long long t2 = __shfl_down(v, s, 64);
    if (lane + s < 64) v += t2;
  }
  if (lane == 0) wsumU[wid] = v;
  __syncthreads();
  unsigned long long woff = (wid == 0) ? wsumU[1] : ((wid == 2) ? wsumU[3] : 0ULL);
  unsigned long long run = woff + (v - S);

  float acc2 = 0.f;
#pragma unroll
  for (int u = 7; u >= 0; --u) {
    run += hh[u];
    const float nf = (float)(unsigned int)(hh[u] >> 32);
    const float sufq = (float)(unsigned int)run;
    acc2 += nf * __log2f(fmaxf(sufq, 1.f));
  }

  for (int s = 32; s; s >>= 1) acc2 += __shfl_down(acc2, s, 64);
  if (lane == 0) redf[wid] = acc2;
  __syncthreads();
  if (tid == 0) {
    const float tf0 = (float)(unsigned int)(wsumU[0] + wsumU[1]);
    const float tf1 = (float)(unsigned int)(wsumU[2] + wsumU[3]);
    part_logd[i] = (redf[0] + redf[1] - 65536.f - __log2f(tf0) + 16.f) * LN2;
    part_logd[MM + i] = (redf[2] + redf[3] - 65536.f - __log2f(tf1) + 16.f) * LN2;
    part_sr[i] = redsr[0] + redsr[1];
  }
}

// ---------------- single-block final reduce (double) ----------------
__global__ __launch_bounds__(256) void kredm(const float* __restrict__ part_logd,
                                             const float* __restrict__ part_sr,
                                             float* __restrict__ out) {
  const int tid = threadIdx.x;
  double s0 = 0.0, s1 = 0.0, ss = 0.0;
#pragma unroll
  for (int q = 0; q < MM / 256; ++q) {
    const int idx = q * 256 + tid;
    s0 += (double)part_logd[idx];
    s1 += (double)part_logd[MM + idx];
    ss += (double)part_sr[idx];
  }
  for (int s = 32; s; s >>= 1) {
    s0 += __shfl_down(s0, s, 64);
    s1 += __shfl_down(s1, s, 64);
    ss += __shfl_down(ss, s, 64);
  }
  __shared__ double red[3][4];
  if ((tid & 63) == 0) {
    red[0][tid >> 6] = s0; red[1][tid >> 6] = s1; red[2][tid >> 6] = ss;
  }
  __syncthreads();
  if (tid == 0) {
    const double t0 = red[0][0] + red[0][1] + red[0][2] + red[0][3];
    const double t1 = red[1][0] + red[1][1] + red[1][2] + red[1][3];
    const double ts = red[2][0] + red[2][1] + red[2][2] + red[2][3];
    const double n = (double)MM * (double)(MM - 1);
    out[0] = (float)((t0 - ts) / n);
    out[1] = (float)((t1 - ts) / n);
  }
}

extern "C" void kernel_launch(void* const* d_in, const int* in_sizes, int n_in,
                              void* d_out, int out_size, void* d_ws, size_t ws_size,
                              hipStream_t stream) {
  const float* emb = (const float*)d_in[0];
  const float* labels = (const float*)d_in[1];
  float* out = (float*)d_out;
  char* ws = (char*)d_ws;

  size_t off = 0;
  auto alloc = [&](size_t bytes) {
    void* p = ws + off;
    off = (off + bytes + 255) & ~(size_t)255;
    return p;
  };
  __hip_bfloat16* nb = (__hip_bfloat16*)alloc((size_t)MM * KK * 2);
  float* dmm = (float*)alloc(4 * 4);
  float* part_logd = (float*)alloc((size_t)2 * MM * 4);
  float* part_sr = (float*)alloc((size_t)MM * 4);
  float* srow = (float*)alloc((size_t)MM * 128 * 4);
  size_t fixed = off;

  size_t avail = (ws_size > fixed) ? (ws_size - fixed) : 0;
  long long cr = (long long)(avail / ((size_t)MM * 2));
  cr = (cr / 128) * 128;
  if (cr > MM) cr = MM;
  if (cr < 128) cr = 128;
  int chunk_rows = (int)cr;
  unsigned short* expb = (unsigned short*)(ws + fixed);

  knorm<<<MM / 4 + 1, 256, 0, stream>>>(emb, nb, labels, dmm);

  if (chunk_rows == MM) {
    kgemm_sym64<<<NB64 * (NB64 + 1) / 2, 256, 0, stream>>>(nb, expb, srow);
    kloss<<<MM, 256, 0, stream>>>(expb, 0, labels, dmm, srow, part_logd, part_sr);
  } else {
    hipMemsetAsync(srow, 0, (size_t)MM * 128 * 4, stream);
    for (int base = 0; base < MM; base += chunk_rows) {
      int rows = MM - base < chunk_rows ? MM - base : chunk_rows;
      kgemm<<<dim3(MM / 128, rows / 128), 256, 0, stream>>>(nb, base, expb, srow);
      kloss<<<rows, 256, 0, stream>>>(expb, base, labels, dmm, srow, part_logd, part_sr);
    }
  }
  kredm<<<1, 256, 0, stream>>>(part_logd, part_sr, out);
}

// Round 19
// 67.643 us; speedup vs baseline: 3.7760x; 1.0234x over previous
//
#include <hip/hip_runtime.h>
#include <hip/hip_bf16.h>
#include <math.h>

#define MM 4096
#define KK 768
#define NB64 64
#define NBK 512
#define QSCALE 65536.0f
#define LN2 0.6931471805599453f

typedef short bf16x8 __attribute__((ext_vector_type(8)));
typedef unsigned short u16x8 __attribute__((ext_vector_type(8)));
typedef float f32x4 __attribute__((ext_vector_type(4)));

__device__ __forceinline__ float bf2f(unsigned short u) {
  return __uint_as_float(((unsigned int)u) << 16);
}
__device__ __forceinline__ unsigned short f2bf(float f) {
  __hip_bfloat16 h = __float2bfloat16(f);
  return *(unsigned short*)&h;
}

__device__ __forceinline__ void gload16(const void* g, void* l) {
#if __has_builtin(__builtin_amdgcn_global_load_lds)
  __builtin_amdgcn_global_load_lds((__attribute__((address_space(1))) void*)g,
                                   (__attribute__((address_space(3))) void*)l,
                                   16, 0, 0);
#else
  *(bf16x8*)l = *(const bf16x8*)g;
#endif
}

// ------- normalize rows -> bf16, 4 rows/block wave-local (+min/max last block) ----
__global__ __launch_bounds__(256) void knorm(const float* __restrict__ emb,
                                             __hip_bfloat16* __restrict__ nb,
                                             const float* __restrict__ labels,
                                             float* __restrict__ dmm) {
  const int tid = threadIdx.x;
  if (blockIdx.x == MM / 4) {  // fused kminmax block
    float mn0 = 1e30f, mx0 = -1e30f, mn1 = 1e30f, mx1 = -1e30f;
    for (int q = tid; q < MM; q += 256) {
      float2 l2 = ((const float2*)labels)[q];
      mn0 = fminf(mn0, l2.x); mx0 = fmaxf(mx0, l2.x);
      mn1 = fminf(mn1, l2.y); mx1 = fmaxf(mx1, l2.y);
    }
    for (int s = 32; s; s >>= 1) {
      mn0 = fminf(mn0, __shfl_down(mn0, s, 64));
      mx0 = fmaxf(mx0, __shfl_down(mx0, s, 64));
      mn1 = fminf(mn1, __shfl_down(mn1, s, 64));
      mx1 = fmaxf(mx1, __shfl_down(mx1, s, 64));
    }
    __shared__ float redm[4][4];
    if ((tid & 63) == 0) {
      redm[0][tid >> 6] = mn0; redm[1][tid >> 6] = mx0;
      redm[2][tid >> 6] = mn1; redm[3][tid >> 6] = mx1;
    }
    __syncthreads();
    if (tid == 0) {
      dmm[0] = fminf(fminf(redm[0][0], redm[0][1]), fminf(redm[0][2], redm[0][3]));
      dmm[1] = fmaxf(fmaxf(redm[1][0], redm[1][1]), fmaxf(redm[1][2], redm[1][3]));
      dmm[2] = fminf(fminf(redm[2][0], redm[2][1]), fminf(redm[2][2], redm[2][3]));
      dmm[3] = fmaxf(fmaxf(redm[3][0], redm[3][1]), fmaxf(redm[3][2], redm[3][3]));
    }
    return;
  }
  const int w = tid >> 6, l = tid & 63;
  const int row = blockIdx.x * 4 + w;
  const float4* e4 = (const float4*)(emb + (size_t)row * KK);
  float4 a = e4[l], b = e4[l + 64], c = e4[l + 128];
  float ss = a.x * a.x + a.y * a.y + a.z * a.z + a.w * a.w +
             b.x * b.x + b.y * b.y + b.z * b.z + b.w * b.w +
             c.x * c.x + c.y * c.y + c.z * c.z + c.w * c.w;
#pragma unroll
  for (int s = 1; s < 64; s <<= 1) ss += __shfl_xor(ss, s, 64);
  const float inv = 1.f / fmaxf(sqrtf(ss), 1e-12f);
  unsigned short* o = (unsigned short*)(nb + (size_t)row * KK);
  ushort4 o1 = {f2bf(a.x * inv), f2bf(a.y * inv), f2bf(a.z * inv), f2bf(a.w * inv)};
  ushort4 o2 = {f2bf(b.x * inv), f2bf(b.y * inv), f2bf(b.z * inv), f2bf(b.w * inv)};
  ushort4 o3 = {f2bf(c.x * inv), f2bf(c.y * inv), f2bf(c.z * inv), f2bf(c.w * inv)};
  *(ushort4*)(o + l * 4) = o1;
  *(ushort4*)(o + 256 + l * 4) = o2;
  *(ushort4*)(o + 512 + l * 4) = o3;
}

// ---------------- symmetric bf16 MFMA GEMM, 64x64 tiles, BK=64 (proven form) -----
union SmemU64 {
  struct { short As[64 * 64]; short Bs[64 * 64]; } s;
  float tbuf[32][68];
};

__global__ __launch_bounds__(256) void kgemm_sym64(const __hip_bfloat16* __restrict__ A,
                                                   unsigned short* __restrict__ out,
                                                   float* __restrict__ srow) {
  __shared__ __align__(16) SmemU64 sm;
  const int tid = threadIdx.x;
  const int w = tid >> 6, l = tid & 63;
  const int wr = w >> 1, wc = w & 1;
  // decode triangular block index -> (by, bx), bx >= by
  const int b = blockIdx.x;
  int by = (int)((129.0f - sqrtf(16641.0f - 8.0f * (float)b)) * 0.5f);
  by = min(max(by, 0), 63);
  while (by > 0 && (by * (129 - by)) / 2 > b) --by;
  while (by < 63 && (((by + 1) * (129 - (by + 1))) / 2) <= b) ++by;
  const int bx = by + (b - (by * (129 - by)) / 2);
  const int row0 = by * 64, col0 = bx * 64;
  const short* Ag = (const short*)A;

  f32x4 acc[2][2];
#pragma unroll
  for (int mi = 0; mi < 2; ++mi)
#pragma unroll
    for (int ni = 0; ni < 2; ++ni) acc[mi][ni] = (f32x4){0.f, 0.f, 0.f, 0.f};

  const int r0 = tid >> 3, s0 = tid & 7;
  const int sx = ((s0 ^ (r0 & 7)) * 8);          // pre-swizzled source column seg
  const int lr = l & 15, kb = (l >> 4) * 8;
  const int xr = (lr & 7) << 3;                  // read-side XOR swizzle

  for (int k0 = 0; k0 < KK; k0 += 64) {
    __syncthreads();
    gload16(Ag + (size_t)(row0 + r0) * KK + k0 + sx, &sm.s.As[tid * 8]);
    gload16(Ag + (size_t)(row0 + 32 + r0) * KK + k0 + sx, &sm.s.As[(tid + 256) * 8]);
    gload16(Ag + (size_t)(col0 + r0) * KK + k0 + sx, &sm.s.Bs[tid * 8]);
    gload16(Ag + (size_t)(col0 + 32 + r0) * KK + k0 + sx, &sm.s.Bs[(tid + 256) * 8]);
    __syncthreads();
    bf16x8 av[2][2], bv[2][2];
#pragma unroll
    for (int mi = 0; mi < 2; ++mi)
#pragma unroll
      for (int kh = 0; kh < 2; ++kh)
        av[mi][kh] = *(const bf16x8*)&sm.s.As[(wr * 32 + mi * 16 + lr) * 64 +
                                              ((kh * 32 + kb) ^ xr)];
#pragma unroll
    for (int ni = 0; ni < 2; ++ni)
#pragma unroll
      for (int kh = 0; kh < 2; ++kh)
        bv[ni][kh] = *(const bf16x8*)&sm.s.Bs[(wc * 32 + ni * 16 + lr) * 64 +
                                              ((kh * 32 + kb) ^ xr)];
#pragma unroll
    for (int kh = 0; kh < 2; ++kh)
#pragma unroll
      for (int mi = 0; mi < 2; ++mi)
#pragma unroll
        for (int ni = 0; ni < 2; ++ni)
          acc[mi][ni] = __builtin_amdgcn_mfma_f32_16x16x32_bf16(av[mi][kh], bv[ni][kh],
                                                                acc[mi][ni], 0, 0, 0);
  }

  const int quad = l >> 4;
  const bool diag = (bx == by);

  // row-sums: slot bx*2 + wc
#pragma unroll
  for (int mi = 0; mi < 2; ++mi) {
#pragma unroll
    for (int r = 0; r < 4; ++r) {
      const int grow = row0 + wr * 32 + mi * 16 + quad * 4 + r;
      float rsum = 0.f;
#pragma unroll
      for (int ni = 0; ni < 2; ++ni) {
        const int gcol = col0 + wc * 32 + ni * 16 + lr;
        rsum += (diag && gcol == grow) ? 0.f : acc[mi][ni][r];
      }
#pragma unroll
      for (int mask = 1; mask < 16; mask <<= 1) rsum += __shfl_xor(rsum, mask, 64);
      if (lr == 0) srow[(size_t)grow * 128 + bx * 2 + wc] = rsum / 0.1f;
    }
  }

  // mirrored row-sums = tile column sums: slot by*2 + wr
  if (!diag) {
#pragma unroll
    for (int ni = 0; ni < 2; ++ni) {
      float csum = 0.f;
#pragma unroll
      for (int mi = 0; mi < 2; ++mi)
#pragma unroll
        for (int r = 0; r < 4; ++r) csum += acc[mi][ni][r];
      csum += __shfl_xor(csum, 16, 64);
      csum += __shfl_xor(csum, 32, 64);
      if (quad == 0)
        srow[(size_t)(col0 + wc * 32 + ni * 16 + l) * 128 + by * 2 + wr] = csum / 0.1f;
    }
  }

  // exp in place
#pragma unroll
  for (int mi = 0; mi < 2; ++mi)
#pragma unroll
    for (int ni = 0; ni < 2; ++ni)
#pragma unroll
      for (int r = 0; r < 4; ++r)
        acc[mi][ni][r] = __expf(acc[mi][ni][r] / 0.1f);

  // normal store (bf16)
#pragma unroll
  for (int mi = 0; mi < 2; ++mi)
#pragma unroll
    for (int r = 0; r < 4; ++r) {
      const int grow = row0 + wr * 32 + mi * 16 + quad * 4 + r;
#pragma unroll
      for (int ni = 0; ni < 2; ++ni)
        out[(size_t)grow * MM + col0 + wc * 32 + ni * 16 + lr] = f2bf(acc[mi][ni][r]);
    }

  // mirrored (transposed) store via LDS, 2 passes of 32 rows
  if (!diag) {
#pragma unroll
    for (int p = 0; p < 2; ++p) {
      __syncthreads();
      if (wc == p) {
#pragma unroll
        for (int ni = 0; ni < 2; ++ni) {
          const int ltr = ni * 16 + lr;
#pragma unroll
          for (int mi = 0; mi < 2; ++mi) {
            const int cbase = wr * 32 + mi * 16 + quad * 4;
#pragma unroll
            for (int r = 0; r < 4; ++r)
              sm.tbuf[ltr][cbase + r] = acc[mi][ni][r];
          }
        }
      }
      __syncthreads();
      const int trow = tid >> 3;
      const int cseg = (tid & 7) * 8;
      const int gtr = col0 + p * 32 + trow;
      u16x8 vv;
#pragma unroll
      for (int q = 0; q < 8; ++q) vv[q] = f2bf(sm.tbuf[trow][cseg + q]);
      *(u16x8*)(out + (size_t)gtr * MM + row0 + cseg) = vv;
    }
  }
}

// ---------------- chunked fallback GEMM (small workspace only) ----------
__global__ __launch_bounds__(256) void kgemm(const __hip_bfloat16* __restrict__ A,
                                             int rowBase,
                                             unsigned short* __restrict__ out,
                                             float* __restrict__ srow) {
  __shared__ __align__(16) short As[128 * 32];
  __shared__ __align__(16) short Bs[128 * 32];
  const int tid = threadIdx.x;
  const int w = tid >> 6, l = tid & 63;
  const int wr = w >> 1, wc = w & 1;
  const int bx = blockIdx.x;
  const int row0 = rowBase + blockIdx.y * 128;
  const int col0 = bx * 128;
  const short* Ag = (const short*)A;

  f32x4 acc[4][4];
#pragma unroll
  for (int mi = 0; mi < 4; ++mi)
#pragma unroll
    for (int ni = 0; ni < 4; ++ni) acc[mi][ni] = (f32x4){0.f, 0.f, 0.f, 0.f};

  const int r0 = tid >> 2, s0 = tid & 3;
  const int r1 = (tid + 256) >> 2;
  const int lrow = l & 15, kb = (l >> 4) * 8;

  for (int k0 = 0; k0 < KK; k0 += 32) {
    __syncthreads();
    gload16(Ag + (size_t)(row0 + r0) * KK + k0 + s0 * 8, &As[tid * 8]);
    gload16(Ag + (size_t)(row0 + r1) * KK + k0 + s0 * 8, &As[(tid + 256) * 8]);
    gload16(Ag + (size_t)(col0 + r0) * KK + k0 + s0 * 8, &Bs[tid * 8]);
    gload16(Ag + (size_t)(col0 + r1) * KK + k0 + s0 * 8, &Bs[(tid + 256) * 8]);
    __syncthreads();
    bf16x8 av[4], bv[4];
#pragma unroll
    for (int mi = 0; mi < 4; ++mi)
      av[mi] = *(const bf16x8*)&As[(wr * 64 + mi * 16 + lrow) * 32 + kb];
#pragma unroll
    for (int ni = 0; ni < 4; ++ni)
      bv[ni] = *(const bf16x8*)&Bs[(wc * 64 + ni * 16 + lrow) * 32 + kb];
#pragma unroll
    for (int mi = 0; mi < 4; ++mi)
#pragma unroll
      for (int ni = 0; ni < 4; ++ni)
        acc[mi][ni] = __builtin_amdgcn_mfma_f32_16x16x32_bf16(av[mi], bv[ni],
                                                              acc[mi][ni], 0, 0, 0);
  }

  const int quad = l >> 4;
#pragma unroll
  for (int mi = 0; mi < 4; ++mi) {
#pragma unroll
    for (int r = 0; r < 4; ++r) {
      const int grow = row0 + wr * 64 + mi * 16 + quad * 4 + r;
      float rsum = 0.f;
#pragma unroll
      for (int ni = 0; ni < 4; ++ni) {
        const int gcol = col0 + wc * 64 + ni * 16 + lrow;
        float a = acc[mi][ni][r];
        out[(size_t)(grow - rowBase) * MM + gcol] = f2bf(__expf(a / 0.1f));
        rsum += (gcol == grow) ? 0.f : a;
      }
#pragma unroll
      for (int mask = 1; mask < 16; mask <<= 1) rsum += __shfl_xor(rsum, mask, 64);
      if (lrow == 0) srow[(size_t)grow * 128 + bx * 2 + wc] = rsum / 0.1f;
    }
  }
}

// ---- per-row loss: dual-dim u64 (count|qsum) histogram + fused srow row-sum -----
__global__ __launch_bounds__(256) void kloss(const unsigned short* __restrict__ expb,
                                             int rowBase,
                                             const float* __restrict__ labels,
                                             const float* __restrict__ dmm,
                                             const float* __restrict__ srow,
                                             float* __restrict__ part_logd,
                                             float* __restrict__ part_sr) {
  const int i = rowBase + blockIdx.x;
  const unsigned short* row = expb + (size_t)blockIdx.x * MM;
  __shared__ __align__(16) unsigned long long histU[2 * NBK];  // dim0 [0,NBK), dim1 [NBK,2NBK)
  __shared__ unsigned long long wsumU[4];
  __shared__ float redf[4];
  __shared__ float redsr[4];
  const int tid = threadIdx.x;
  const int lane = tid & 63, wid = tid >> 6;
  const int m0 = tid * 16;
  const int b0 = tid * 4;   // 4 u64 buckets/thread over 2*NBK=1024;
                            // dim boundary (512) falls exactly at wave-2 boundary

  // fused srow row-sum (512 B coalesced, hidden under histogram work)
  float sv = (tid < 128) ? srow[(size_t)i * 128 + tid] : 0.f;
  for (int s = 32; s; s >>= 1) sv += __shfl_down(sv, s, 64);
  if (lane == 0) redsr[wid] = sv;

  const float c0 = labels[(size_t)i * 2], c1 = labels[(size_t)i * 2 + 1];
  const float tmax0 = fmaxf(fmaxf(c0 - dmm[0], dmm[1] - c0), 1e-30f);
  const float tmax1 = fmaxf(fmaxf(c1 - dmm[2], dmm[3] - c1), 1e-30f);
  const float scale0 = (float)NBK / tmax0;
  const float scale1 = (float)NBK / tmax1;

  // zero both histograms (1024 u64 = 512 uint4)
  ((uint4*)histU)[tid] = (uint4){0, 0, 0, 0};
  ((uint4*)histU)[tid + 256] = (uint4){0, 0, 0, 0};
  __syncthreads();

  {
    u16x8 a = *(const u16x8*)(row + m0);
    u16x8 bq = *(const u16x8*)(row + m0 + 8);
    const float4* lp4 = (const float4*)(labels + (size_t)m0 * 2);
#pragma unroll
    for (int q = 0; q < 8; ++q) {
      float4 v4 = lp4[q];
      const unsigned short r0u = (2 * q < 8) ? a[2 * q] : bq[2 * q - 8];
      const unsigned short r1u = (2 * q + 1 < 8) ? a[2 * q + 1] : bq[2 * q + 1 - 8];
      const unsigned long long g0 =
          (unsigned long long)(unsigned int)(bf2f(r0u) * QSCALE + 0.5f) | (1ULL << 32);
      const unsigned long long g1 =
          (unsigned long long)(unsigned int)(bf2f(r1u) * QSCALE + 0.5f) | (1ULL << 32);
      const int a0 = min((int)(fabsf(v4.x - c0) * scale0), NBK - 1);
      const int a1 = min((int)(fabsf(v4.y - c1) * scale1), NBK - 1);
      const int b2 = min((int)(fabsf(v4.z - c0) * scale0), NBK - 1);
      const int b3 = min((int)(fabsf(v4.w - c1) * scale1), NBK - 1);
      atomicAdd(&histU[a0], g0);
      atomicAdd(&histU[NBK + a1], g0);
      atomicAdd(&histU[b2], g1);
      atomicAdd(&histU[NBK + b3], g1);
    }
  }
  __syncthreads();

  // u64 suffix scan over own 4 buckets; waves 0-1 = dim0, waves 2-3 = dim1
  unsigned long long hh[4];
  {
    uint4 t4a = *(const uint4*)&histU[b0];
    uint4 t4b = *(const uint4*)&histU[b0 + 2];
    hh[0] = (unsigned long long)t4a.x | ((unsigned long long)t4a.y << 32);
    hh[1] = (unsigned long long)t4a.z | ((unsigned long long)t4a.w << 32);
    hh[2] = (unsigned long long)t4b.x | ((unsigned long long)t4b.y << 32);
    hh[3] = (unsigned long long)t4b.z | ((unsigned long long)t4b.w << 32);
  }
  unsigned long long S = hh[0] + hh[1] + hh[2] + hh[3];
  unsigned long long v = S;
#pragma unroll
  for (int s = 1; s < 64; s <<= 1) {
    unsigned long long t2 = __shfl_down(v, s, 64);
    if (lane + s < 64) v += t2;
  }
  if (lane == 0) wsumU[wid] = v;
  __syncthreads();
  // suffix offset: wave0 needs wave1's range-sum (dim0 upper half); wave2 needs wave3's
  unsigned long long woff = (wid == 0) ? wsumU[1] : ((wid == 2) ? wsumU[3] : 0ULL);
  unsigned long long run = woff + (v - S);

  // count-weighted log pass — fully register-local
  float acc2 = 0.f;
#pragma unroll
  for (int u = 3; u >= 0; --u) {
    run += hh[u];                                   // run = SUF over buckets >= b0+u
    const float nf = (float)(unsigned int)(hh[u] >> 32);
    const float sufq = (float)(unsigned int)run;    // qval part (< 2^32, no carry)
    acc2 += nf * __log2f(fmaxf(sufq, 1.f));
  }

  for (int s = 32; s; s >>= 1) acc2 += __shfl_down(acc2, s, 64);
  if (lane == 0) redf[wid] = acc2;
  __syncthreads();
  if (tid == 0) {
    // part = ln2 * ( sum_b n_b*log2(SUF_b) - 4096*16 - log2(total) + 16 )
    const float tf0 = (float)(unsigned int)(wsumU[0] + wsumU[1]);
    const float tf1 = (float)(unsigned int)(wsumU[2] + wsumU[3]);
    part_logd[i] = (redf[0] + redf[1] - 65536.f - __log2f(tf0) + 16.f) * LN2;
    part_logd[MM + i] = (redf[2] + redf[3] - 65536.f - __log2f(tf1) + 16.f) * LN2;
    part_sr[i] = redsr[0] + redsr[1];
  }
}

// ---------------- single-block final reduce (double) ----------------
__global__ __launch_bounds__(256) void kredm(const float* __restrict__ part_logd,
                                             const float* __restrict__ part_sr,
                                             float* __restrict__ out) {
  const int tid = threadIdx.x;
  double s0 = 0.0, s1 = 0.0, ss = 0.0;
#pragma unroll
  for (int q = 0; q < MM / 256; ++q) {
    const int idx = q * 256 + tid;
    s0 += (double)part_logd[idx];
    s1 += (double)part_logd[MM + idx];
    ss += (double)part_sr[idx];
  }
  for (int s = 32; s; s >>= 1) {
    s0 += __shfl_down(s0, s, 64);
    s1 += __shfl_down(s1, s, 64);
    ss += __shfl_down(ss, s, 64);
  }
  __shared__ double red[3][4];
  if ((tid & 63) == 0) {
    red[0][tid >> 6] = s0; red[1][tid >> 6] = s1; red[2][tid >> 6] = ss;
  }
  __syncthreads();
  if (tid == 0) {
    const double t0 = red[0][0] + red[0][1] + red[0][2] + red[0][3];
    const double t1 = red[1][0] + red[1][1] + red[1][2] + red[1][3];
    const double ts = red[2][0] + red[2][1] + red[2][2] + red[2][3];
    const double n = (double)MM * (double)(MM - 1);
    out[0] = (float)((t0 - ts) / n);
    out[1] = (float)((t1 - ts) / n);
  }
}

extern "C" void kernel_launch(void* const* d_in, const int* in_sizes, int n_in,
                              void* d_out, int out_size, void* d_ws, size_t ws_size,
                              hipStream_t stream) {
  const float* emb = (const float*)d_in[0];
  const float* labels = (const float*)d_in[1];
  float* out = (float*)d_out;
  char* ws = (char*)d_ws;

  size_t off = 0;
  auto alloc = [&](size_t bytes) {
    void* p = ws + off;
    off = (off + bytes + 255) & ~(size_t)255;
    return p;
  };
  __hip_bfloat16* nb = (__hip_bfloat16*)alloc((size_t)MM * KK * 2);
  float* dmm = (float*)alloc(4 * 4);
  float* part_logd = (float*)alloc((size_t)2 * MM * 4);
  float* part_sr = (float*)alloc((size_t)MM * 4);
  float* srow = (float*)alloc((size_t)MM * 128 * 4);
  double* red3 = (double*)alloc((size_t)64 * 3 * 8);
  size_t fixed = off;

  size_t avail = (ws_size > fixed) ? (ws_size - fixed) : 0;
  long long cr = (long long)(avail / ((size_t)MM * 2));
  cr = (cr / 128) * 128;
  if (cr > MM) cr = MM;
  if (cr < 128) cr = 128;
  int chunk_rows = (int)cr;
  unsigned short* expb = (unsigned short*)(ws + fixed);

  knorm<<<MM / 4 + 1, 256, 0, stream>>>(emb, nb, labels, dmm);

  if (chunk_rows == MM) {
    kgemm_sym64<<<NB64 * (NB64 + 1) / 2, 256, 0, stream>>>(nb, expb, srow);
    kloss<<<MM, 256, 0, stream>>>(expb, 0, labels, dmm, srow, part_logd, part_sr);
  } else {
    hipMemsetAsync(srow, 0, (size_t)MM * 128 * 4, stream);
    for (int base = 0; base < MM; base += chunk_rows) {
      int rows = MM - base < chunk_rows ? MM - base : chunk_rows;
      kgemm<<<dim3(MM / 128, rows / 128), 256, 0, stream>>>(nb, base, expb, srow);
      kloss<<<rows, 256, 0, stream>>>(expb, base, labels, dmm, srow, part_logd, part_sr);
    }
  }
  kredm<<<1, 256, 0, stream>>>(part_logd, part_sr, out);
}